// Round 3
// baseline (180.877 us; speedup 1.0000x reference)
//
#include <hip/hip_runtime.h>
#include <cmath>

// SSIM fused kernel for B=16, C=3, H=W=512 fp32 images.
// R3: re-tile from (32 rows x 512 cols, 512 threads) to (128 x 128, 128
// threads). Halo overhead drops 1.34x -> 1.16x (-12% VALU, -18% LDS), and
// 2-wave blocks at ~2.3 KB LDS give ~10+ co-resident blocks/CU so the
// per-row barrier bubbles (the measured 28% VALU idle at only 2 blocks/CU)
// are filled by other blocks' work.
// R2 lesson kept: f32x2 packed ring (VGPR 52->36). R1 lesson kept: never
// let the ring spill (WRITE_SIZE is the sentinel).
// Inner algorithm unchanged: stage row into float2 LDS (double-buffered),
// 11-tap horizontal conv of (a,b)/(a^2+b^2,ab), vertical via 11-deep
// register ring with static (j+1+k)%11 indexing.

#define IMG_H 512
#define IMG_W 512
#define BR 128                     // output rows per block
#define BC 128                     // output cols per block
#define SR (BR + 10)               // staged rows = 138
#define SC (BC + 10)               // staged cols = 138
#define NRB (IMG_H / BR)           // 4
#define NCB (IMG_W / BC)           // 4
#define NPLANES 48                 // 16*3
#define NBLOCKS (NPLANES * NRB * NCB)   // 768
#define SSIM_C1 (0.01f * 0.01f)
#define SSIM_C2 (0.03f * 0.03f)

typedef float f32x2 __attribute__((ext_vector_type(2)));

struct W2x11 { float2 w[11]; };   // pre-broadcast {w,w} pairs

__launch_bounds__(128, 6)
__global__ void ssim_main(const float* __restrict__ img1,
                          const float* __restrict__ img2,
                          float* __restrict__ blockSums, W2x11 wv) {
    // slot s holds col (x0 - 5 + s) as interleaved (a,b); 138 slots used
    __shared__ float2 tb[2][SC + 2];
    __shared__ float red[2];

    const int t = threadIdx.x;            // 0..127, output col x0+t
    const int bid = blockIdx.x;
    const int plane = bid >> 4;
    const int rb = (bid >> 2) & 3;
    const int cb = bid & 3;
    const int y0 = rb * BR;
    const int x0 = cb * BC;
    const size_t base = (size_t)plane * (IMG_H * IMG_W);

    // staged columns: main slot t -> col x0-5+t; extra slot BC+t (t<10)
    const int c1 = x0 - 5 + t;
    const int c2 = x0 + BC - 5 + t;
    const bool c1ok = (c1 >= 0) && (c1 < IMG_W);
    const bool e2 = (t < 10);
    const bool c2ok = e2 && (c2 < IMG_W);

    // vertical ring buffers as packed pairs, static-indexed via unroll
    f32x2 rAB[11], rSP[11];
    float acc = 0.f;

    // prefetch first row (r = y0-5)
    float pa = 0.f, pb = 0.f, qa = 0.f, qb = 0.f;
    {
        const int r0 = y0 - 5;
        if (r0 >= 0) {
            const size_t rowb = base + (size_t)r0 * IMG_W;
            if (c1ok) { pa = img1[rowb + c1]; pb = img2[rowb + c1]; }
            if (c2ok) { qa = img1[rowb + c2]; qb = img2[rowb + c2]; }
        }
    }

    int buf = 0;
#pragma unroll 1
    for (int c = 0; c < 13; ++c) {       // 13*11 = 143 slots; work for i<138
#pragma unroll
        for (int j = 0; j < 11; ++j) {
            const int i = c * 11 + j;    // staged-row index 0..137
            if (i < SR) {                // block-uniform guard
                // stage current row into LDS
                tb[buf][t] = make_float2(pa, pb);
                if (e2) tb[buf][BC + t] = make_float2(qa, qb);
                // prefetch next row (hidden behind barrier + compute)
                pa = 0.f; pb = 0.f; qa = 0.f; qb = 0.f;
                const int rn = y0 - 4 + i;
                if (i + 1 < SR && rn >= 0 && rn < IMG_H) {
                    const size_t rowb = base + (size_t)rn * IMG_W;
                    if (c1ok) { pa = img1[rowb + c1]; pb = img2[rowb + c1]; }
                    if (c2ok) { qa = img1[rowb + c2]; qb = img2[rowb + c2]; }
                }
                __syncthreads();
                // horizontal 11-tap conv; (A,B) and (S,P) packed
                f32x2 hAB = {0.f, 0.f}, hSP = {0.f, 0.f};
#pragma unroll
                for (int k = 0; k < 11; ++k) {
                    const float2 v = tb[buf][t + k];   // ds_read_b64
                    f32x2 ab; ab.x = v.x; ab.y = v.y;
                    f32x2 sp;
                    sp.x = fmaf(v.y, v.y, v.x * v.x);  // a^2+b^2
                    sp.y = v.x * v.y;                  // a*b
                    f32x2 w2; w2.x = wv.w[k].x; w2.y = wv.w[k].y;
                    hAB = __builtin_elementwise_fma(w2, ab, hAB);
                    hSP = __builtin_elementwise_fma(w2, sp, hSP);
                }
                rAB[j] = hAB; rSP[j] = hSP;

                if (i >= 10) {  // uniform; output row y = y0 + i - 10
                    f32x2 vAB = {0.f, 0.f}, vSP = {0.f, 0.f};
#pragma unroll
                    for (int k = 0; k < 11; ++k) {
                        const int s = (j + 1 + k) % 11;  // static per (j,k)
                        f32x2 w2; w2.x = wv.w[k].x; w2.y = wv.w[k].y;
                        vAB = __builtin_elementwise_fma(w2, rAB[s], vAB);
                        vSP = __builtin_elementwise_fma(w2, rSP[s], vSP);
                    }
                    const float vA = vAB.x, vB = vAB.y;
                    const float vS = vSP.x, vP = vSP.y;
                    const float mu11 = vA * vA;
                    const float mu22 = vB * vB;
                    const float mu12 = vA * vB;
                    const float num = fmaf(2.f, mu12, SSIM_C1) *
                                      fmaf(2.f, vP - mu12, SSIM_C2);
                    const float d1  = mu11 + mu22;
                    const float den = (d1 + SSIM_C1) * ((vS - d1) + SSIM_C2);
                    acc = fmaf(num, __builtin_amdgcn_rcpf(den), acc);
                }
                buf ^= 1;
            }
        }
    }

    // block reduction: wave shuffle, then 2 wave-sums via LDS
#pragma unroll
    for (int off = 32; off >= 1; off >>= 1)
        acc += __shfl_down(acc, off, 64);
    const int wave = t >> 6, lane = t & 63;
    if (lane == 0) red[wave] = acc;
    __syncthreads();
    if (t == 0) blockSums[bid] = red[0] + red[1];
}

__global__ void ssim_reduce(const float* __restrict__ bs,
                            float* __restrict__ out) {
    __shared__ double red[4];
    const int t = threadIdx.x;  // 256 threads
    double a = 0.0;
    for (int idx = t; idx < NBLOCKS; idx += 256) a += (double)bs[idx];
#pragma unroll
    for (int off = 32; off >= 1; off >>= 1)
        a += __shfl_down(a, off, 64);
    const int wave = t >> 6, lane = t & 63;
    if (lane == 0) red[wave] = a;
    __syncthreads();
    if (t == 0) {
        const double s = red[0] + red[1] + red[2] + red[3];
        out[0] = (float)(s / (double)((double)NPLANES * IMG_H * IMG_W));
    }
}

extern "C" void kernel_launch(void* const* d_in, const int* in_sizes, int n_in,
                              void* d_out, int out_size, void* d_ws, size_t ws_size,
                              hipStream_t stream) {
    const float* img1 = (const float*)d_in[0];
    const float* img2 = (const float*)d_in[1];
    float* out = (float*)d_out;
    float* bs = (float*)d_ws;   // 768 floats of scratch

    // Gaussian weights, faithful to reference: center 5.5, sigma 1.5
    W2x11 wv;
    double g[11], s = 0.0;
    for (int i = 0; i < 11; ++i) {
        const double d = (double)i - 5.5;
        g[i] = exp(-(d * d) / (2.0 * 1.5 * 1.5));
        s += g[i];
    }
    for (int i = 0; i < 11; ++i) {
        const float w = (float)(g[i] / s);
        wv.w[i] = make_float2(w, w);
    }

    ssim_main<<<NBLOCKS, 128, 0, stream>>>(img1, img2, bs, wv);
    ssim_reduce<<<1, 256, 0, stream>>>(bs, out);
}

// Round 4
// 157.445 us; speedup vs baseline: 1.1488x; 1.1488x over previous
//
#include <hip/hip_runtime.h>
#include <cmath>

// SSIM fused kernel for B=16, C=3, H=W=512 fp32 images.
// R4: vertical-FIRST separable conv on the proven 512-thread / 32x512
// stripe skeleton (R3's 128x128 tiling starved the chip: 1536 waves total
// = 6/CU, occupancy 15%, 95 us. Reverted.)
//  - Ring now holds RAW (a,b) and (a^2+b^2, ab) as f32x2 pairs; per staged
//    row cost is just 2 loads + 3 VALU, so the 10 halo rows are ~free
//    (R2 paid the 77-instr horizontal conv on all 42 staged rows).
//  - Per OUTPUT row: V-conv (22 pk-fma) -> float4 to LDS -> barrier ->
//    11x ds_read_b128 -> H-conv (22 pk-fma) -> epilogue.
//  - Core VALU/thread: 42x3 + 32x88 = 2942 vs R2's 42x77+32x44 = 4642.
//  - Barriers 42 -> 32 per block. Parallelism unchanged (24 waves/CU cap).
// Sentinels: WRITE_SIZE must stay ~24 KB (no spill); VALUBusy < 55% would
// mean the 1.5x LDS-byte increase became the bottleneck.

#define IMG_H 512
#define IMG_W 512
#define STRIPE 32
#define NSTR (IMG_H / STRIPE)      // 16
#define NPLANES 48                 // 16*3
#define NBLOCKS (NPLANES * NSTR)   // 768
#define SSIM_C1 (0.01f * 0.01f)
#define SSIM_C2 (0.03f * 0.03f)

typedef float f32x2 __attribute__((ext_vector_type(2)));

struct W2x11 { float2 w[11]; };   // pre-broadcast {w,w} pairs

__launch_bounds__(512, 2)
__global__ void ssim_main(const float* __restrict__ img1,
                          const float* __restrict__ img2,
                          float* __restrict__ blockSums, W2x11 wv) {
    // slot s holds V-filtered float4 (vA,vB,vS,vP) of col s-5; pad 528
    __shared__ float4 tb[2][528];
    __shared__ float red[8];

    const int x = threadIdx.x;            // 0..511, one output column
    const int bid = blockIdx.x;
    const int plane = bid >> 4;           // /NSTR
    const int stripe = bid & (NSTR - 1);
    const int y0 = stripe * STRIPE;
    const size_t base = (size_t)plane * (IMG_H * IMG_W);

    // zero halo pads (slots 0..4 and 517..521, both buffers)
    if (x < 10) {
        const int col = (x < 5) ? x : (x + 512);
        tb[0][col] = make_float4(0.f, 0.f, 0.f, 0.f);
        tb[1][col] = make_float4(0.f, 0.f, 0.f, 0.f);
    }

    // vertical ring of RAW packed pairs, static-indexed via unroll
    f32x2 rAB[11], rSP[11];
    float acc = 0.f;

    // prefetch first row (r = y0-5)
    float pa = 0.f, pb = 0.f;
    {
        const int r0 = y0 - 5;
        if (r0 >= 0) {
            pa = img1[base + (size_t)r0 * IMG_W + x];
            pb = img2[base + (size_t)r0 * IMG_W + x];
        }
    }

    int buf = 0;
#pragma unroll 1
    for (int c = 0; c < 4; ++c) {
#pragma unroll
        for (int j = 0; j < 11; ++j) {
            const int i = c * 11 + j;      // 0..43; only 0..41 do work
            if (i < 42) {                  // block-uniform guard
                // push raw row into ring (sq/pr computed ONCE per pixel)
                f32x2 ab; ab.x = pa; ab.y = pb;
                f32x2 sp;
                sp.x = fmaf(pb, pb, pa * pa);   // a^2+b^2
                sp.y = pa * pb;                 // a*b
                rAB[j] = ab; rSP[j] = sp;
                // prefetch next row (hidden behind compute)
                pa = 0.f; pb = 0.f;
                const int rn = y0 - 4 + i;
                if (i + 1 < 42 && rn >= 0 && rn < IMG_H) {
                    pa = img1[base + (size_t)rn * IMG_W + x];
                    pb = img2[base + (size_t)rn * IMG_W + x];
                }

                if (i >= 10) {  // uniform; output row y = y0 + i - 10
                    // vertical 11-tap conv over the ring
                    f32x2 vAB = {0.f, 0.f}, vSP = {0.f, 0.f};
#pragma unroll
                    for (int k = 0; k < 11; ++k) {
                        const int s = (j + 1 + k) % 11;  // static per (j,k)
                        f32x2 w2; w2.x = wv.w[k].x; w2.y = wv.w[k].y;
                        vAB = __builtin_elementwise_fma(w2, rAB[s], vAB);
                        vSP = __builtin_elementwise_fma(w2, rSP[s], vSP);
                    }
                    tb[buf][x + 5] = make_float4(vAB.x, vAB.y, vSP.x, vSP.y);
                    __syncthreads();
                    // horizontal 11-tap conv on V-filtered quads
                    f32x2 hAB = {0.f, 0.f}, hSP = {0.f, 0.f};
#pragma unroll
                    for (int k = 0; k < 11; ++k) {
                        const float4 q = tb[buf][x + k];   // ds_read_b128
                        f32x2 qab; qab.x = q.x; qab.y = q.y;
                        f32x2 qsp; qsp.x = q.z; qsp.y = q.w;
                        f32x2 w2; w2.x = wv.w[k].x; w2.y = wv.w[k].y;
                        hAB = __builtin_elementwise_fma(w2, qab, hAB);
                        hSP = __builtin_elementwise_fma(w2, qsp, hSP);
                    }
                    const float vA = hAB.x, vB = hAB.y;
                    const float vS = hSP.x, vP = hSP.y;
                    const float mu11 = vA * vA;
                    const float mu22 = vB * vB;
                    const float mu12 = vA * vB;
                    const float num = fmaf(2.f, mu12, SSIM_C1) *
                                      fmaf(2.f, vP - mu12, SSIM_C2);
                    const float d1  = mu11 + mu22;
                    const float den = (d1 + SSIM_C1) * ((vS - d1) + SSIM_C2);
                    acc = fmaf(num, __builtin_amdgcn_rcpf(den), acc);
                    buf ^= 1;
                }
            }
        }
    }

    // block reduction: wave shuffle, then 8 wave-sums via LDS
#pragma unroll
    for (int off = 32; off >= 1; off >>= 1)
        acc += __shfl_down(acc, off, 64);
    const int wave = x >> 6, lane = x & 63;
    if (lane == 0) red[wave] = acc;
    __syncthreads();
    if (x == 0) {
        float s = 0.f;
#pragma unroll
        for (int k = 0; k < 8; ++k) s += red[k];
        blockSums[bid] = s;
    }
}

__global__ void ssim_reduce(const float* __restrict__ bs,
                            float* __restrict__ out) {
    __shared__ double red[4];
    const int t = threadIdx.x;  // 256 threads
    double a = 0.0;
    for (int idx = t; idx < NBLOCKS; idx += 256) a += (double)bs[idx];
#pragma unroll
    for (int off = 32; off >= 1; off >>= 1)
        a += __shfl_down(a, off, 64);
    const int wave = t >> 6, lane = t & 63;
    if (lane == 0) red[wave] = a;
    __syncthreads();
    if (t == 0) {
        const double s = red[0] + red[1] + red[2] + red[3];
        out[0] = (float)(s / (double)((double)NPLANES * IMG_H * IMG_W));
    }
}

extern "C" void kernel_launch(void* const* d_in, const int* in_sizes, int n_in,
                              void* d_out, int out_size, void* d_ws, size_t ws_size,
                              hipStream_t stream) {
    const float* img1 = (const float*)d_in[0];
    const float* img2 = (const float*)d_in[1];
    float* out = (float*)d_out;
    float* bs = (float*)d_ws;   // 768 floats of scratch

    // Gaussian weights, faithful to reference: center 5.5, sigma 1.5
    W2x11 wv;
    double g[11], s = 0.0;
    for (int i = 0; i < 11; ++i) {
        const double d = (double)i - 5.5;
        g[i] = exp(-(d * d) / (2.0 * 1.5 * 1.5));
        s += g[i];
    }
    for (int i = 0; i < 11; ++i) {
        const float w = (float)(g[i] / s);
        wv.w[i] = make_float2(w, w);
    }

    ssim_main<<<NBLOCKS, 512, 0, stream>>>(img1, img2, bs, wv);
    ssim_reduce<<<1, 256, 0, stream>>>(bs, out);
}